// Round 19
// baseline (495.202 us; speedup 1.0000x reference)
//
#include <hip/hip_runtime.h>

#define DEVINLINE __device__ __forceinline__

typedef unsigned short u16;
typedef _Float16 f16;
typedef __attribute__((ext_vector_type(8))) _Float16 half8v;
typedef __attribute__((ext_vector_type(4))) float float4v;

constexpr int HID = 128;
constexpr int NSPLIT = 16;    // main-pass column splits
constexpr int BUDS = 24;      // candidate budget per (split, query)
constexpr int BUD = NSPLIT * BUDS;   // 384 total select capacity
constexpr int SMP = 2048;     // sample size for tau (larger -> tighter tau -> fewer survivors)
constexpr int SSPL = 8;       // sample row-splits (grid parallelism)
constexpr int SEGS = 32;      // fallback scan segments per query
constexpr int MAXF = 2048;    // fast-fallback capacity (scratch-sized)

// ---------- small helpers ----------
DEVINLINE void gld16(const void* g, void* l) {
    __builtin_amdgcn_global_load_lds((const __attribute__((address_space(1))) unsigned int*)g,
                                     (__attribute__((address_space(3))) unsigned int*)l, 16, 0, 0);
}
DEVINLINE void gld4(const void* g, void* l) {
    __builtin_amdgcn_global_load_lds((const __attribute__((address_space(1))) unsigned int*)g,
                                     (__attribute__((address_space(3))) unsigned int*)l, 4, 0, 0);
}
// rigorous |d - d~| (distance units) bound for f16 screening metric
DEVINLINE float err_E(float sqq, float sqm) {
    return 6.2e-4f * (sqrtf(sqq) + sqrtf(sqm)) + 0.02f;
}
// rigorous |fp32_d2 - exact_d2| bound for the select rescore
DEVINLINE float eps_sel(float d) { return 2e-6f * (d + 1.f); }
// ascending value-only top-K list (static indices)
template<int K>
DEVINLINE void topk_insert_v(float (&bd)[K], float d) {
    if (d >= bd[K - 1]) return;
#pragma unroll
    for (int p = 0; p < K; ++p) {
        const float mn = fminf(d, bd[p]);
        const float mx = fmaxf(d, bd[p]);
        bd[p] = mn; d = mx;
    }
}
DEVINLINE bool lexd(double d1, int i1, double d2, int i2) {
    return (d1 < d2) || ((d1 == d2) && (i1 < i2));
}
DEVINLINE bool lexf(float d1, int i1, float d2, int i2) {
    return (d1 < d2) || ((d1 == d2) && (i1 < i2));
}
template<int K>
DEVINLINE void topk_insert_d(double (&bd)[K], int (&bi)[K], double d, int j) {
    if (!lexd(d, j, bd[K - 1], bi[K - 1])) return;
    double cd = d; int ci = j;
#pragma unroll
    for (int p = 0; p < K; ++p) {
        const bool lt = lexd(cd, ci, bd[p], bi[p]);
        const double sd = bd[p]; const int si = bi[p];
        bd[p] = lt ? cd : sd;  bi[p] = lt ? ci : si;
        cd = lt ? sd : cd;     ci = lt ? si : ci;
    }
}
template<int K>
DEVINLINE void topk_insert_f(float (&bd)[K], int (&bi)[K], float d, int j) {
    if (!lexf(d, j, bd[K - 1], bi[K - 1])) return;
    float cd = d; int ci = j;
#pragma unroll
    for (int p = 0; p < K; ++p) {
        const bool lt = lexf(cd, ci, bd[p], bi[p]);
        const float sd = bd[p]; const int si = bi[p];
        bd[p] = lt ? cd : sd;  bi[p] = lt ? ci : si;
        cd = lt ? sd : cd;     ci = lt ? si : ci;
    }
}

// ---------------- per-layer init ----------------
__global__ void zero_misc_kernel(int* __restrict__ novf, float* __restrict__ sqmax) {
    if (blockIdx.x == 0 && threadIdx.x == 0) { novf[0] = 0; *(int*)sqmax = 0; }
}

// ---------------- fp32 -> fp16 plane + f16 norms ----------------
template<int D>
__global__ void conv_f16_kernel(const float* __restrict__ X, u16* __restrict__ Xh,
                                float* __restrict__ sqh, float* __restrict__ sqmax, int n) {
    const int i = blockIdx.x * 256 + threadIdx.x;
    float s = 0.f;
    if (i < n) {
        const float4* row = (const float4*)(X + (size_t)i * D);
        ushort4* dst = (ushort4*)(Xh + (size_t)i * D);
#pragma unroll
        for (int u = 0; u < D / 4; ++u) {
            const float4 v = row[u];
            const f16 h0 = (f16)v.x, h1 = (f16)v.y, h2 = (f16)v.z, h3 = (f16)v.w;
            const float f0 = (float)h0, f1 = (float)h1, f2 = (float)h2, f3 = (float)h3;
            s += f0 * f0 + f1 * f1 + f2 * f2 + f3 * f3;
            ushort4 o = {__builtin_bit_cast(u16, h0), __builtin_bit_cast(u16, h1),
                         __builtin_bit_cast(u16, h2), __builtin_bit_cast(u16, h3)};
            dst[u] = o;
        }
        sqh[i] = s;
    }
    float m = (i < n) ? s : 0.f;
#pragma unroll
    for (int off = 32; off >= 1; off >>= 1) m = fmaxf(m, __shfl_xor(m, off, 64));
    if ((threadIdx.x & 63) == 0) atomicMax((int*)sqmax, __float_as_int(m));
}

// ---------------- sample pass: row-split x SSPL, exact-f16-metric top-K ----------------
template<int D, int K>
__global__ __launch_bounds__(256)
void sample_knn_kernel(const u16* __restrict__ Xh, const float* __restrict__ sqh,
                       float* __restrict__ smp, int n, int sstr) {
    constexpr int MB = 64, NMI = 4;
    constexpr int KS = D / 32, SLOTS = D / 8;
    constexpr int TS = MB * SLOTS, TB = TS * 16, SI = TS / 256;
    constexpr int BUFB = TB + 256;
    constexpr int SROWS = SMP / SSPL;   // 256
    constexpr int NT = SROWS / MB;      // 4
    __shared__ __align__(16) char smem[2 * BUFB];

    const int tid = threadIdx.x, lane = tid & 63, wid = tid >> 6;
    const int lrow = lane & 15, lhalf = lane >> 4;
    const int q0 = blockIdx.x * 64, sp = blockIdx.y;
    const int sbeg = sp * SROWS;
    const int q = q0 + wid * 16 + lrow, qc = min(q, n - 1);

    half8v qf[KS];
#pragma unroll
    for (int ks = 0; ks < KS; ++ks)
        qf[ks] = *(const half8v*)(Xh + (size_t)qc * D + (ks * 4 + lhalf) * 8);
    const float sqq = sqh[qc];

    int srow[SI], soff[SI];
#pragma unroll
    for (int it = 0; it < SI; ++it) {
        const int gs = (it * 4 + wid) * 64 + lane;
        const int row = gs / SLOTS, psl = gs % SLOTS;
        const int ksl = (psl & ~7) | ((psl ^ row) & 7);
        srow[it] = row; soff[it] = ksl * 8;
    }

    float bd[K];
#pragma unroll
    for (int p = 0; p < K; ++p) bd[p] = __builtin_inff();

    auto stage = [&](int t, int b) {
        char* buf = smem + b * BUFB;
        const int s0 = sbeg + t * MB;
#pragma unroll
        for (int it = 0; it < SI; ++it) {
            const size_t phys = (size_t)(s0 + srow[it]) * sstr;
            gld16(Xh + phys * D + soff[it], buf + (it * 4 + wid) * 1024);
        }
        if (wid == 0) gld4(sqh + (size_t)(s0 + lane) * sstr, buf + TB);
    };
    auto compute = [&](int t, int b) {
        const char* buf = smem + b * BUFB;
        const u16* hp = (const u16*)buf;
        const float* sql = (const float*)(buf + TB);
        const int s0 = sbeg + t * MB;
        float4v acc[NMI];
#pragma unroll
        for (int mi = 0; mi < NMI; ++mi) acc[mi] = (float4v){0.f, 0.f, 0.f, 0.f};
#pragma unroll
        for (int ks = 0; ks < KS; ++ks) {
#pragma unroll
            for (int mi = 0; mi < NMI; ++mi) {
                const int row = mi * 16 + lrow;
                const int ksl = ks * 4 + lhalf;
                const int pk = (ksl & ~7) | ((ksl ^ row) & 7);
                const half8v af = *(const half8v*)(hp + (size_t)row * (SLOTS * 8) + pk * 8);
                acc[mi] = __builtin_amdgcn_mfma_f32_16x16x32_f16(af, qf[ks], acc[mi], 0, 0, 0);
            }
        }
#pragma unroll
        for (int mi = 0; mi < NMI; ++mi) {
            const float4 s4 = *(const float4*)(sql + mi * 16 + lhalf * 4);
            const float ss[4] = {s4.x, s4.y, s4.z, s4.w};
#pragma unroll
            for (int r = 0; r < 4; ++r) {
                const int sidx = s0 + mi * 16 + lhalf * 4 + r;
                const int j = sidx * sstr;
                const float d2 = sqq + ss[r] - 2.f * acc[mi][r];
                if (j != q) topk_insert_v<K>(bd, d2);
            }
        }
    };

    stage(0, 0);
    __syncthreads();
    for (int t = 0; t < NT; ++t) {
        if (t + 1 < NT) stage(t + 1, (t + 1) & 1);
        compute(t, t & 1);
        __syncthreads();
    }

    if (q < n) {
        const size_t base = ((size_t)(q * SSPL + sp) * 4 + lhalf) * K;
#pragma unroll
        for (int p = 0; p < K; ++p) smp[base + p] = bd[p];
    }
}

// ---------------- merge sample lists -> raw s~ (kth sample screened d2) ----------------
template<int K>
__global__ void tau_merge_kernel(const float* __restrict__ smp, float* __restrict__ tau, int n) {
    const int q = blockIdx.x * 256 + threadIdx.x;
    if (q >= n) return;
    float bd[K];
#pragma unroll
    for (int p = 0; p < K; ++p) bd[p] = __builtin_inff();
    for (int g = 0; g < SSPL * 4; ++g) {
        const size_t base = ((size_t)(q * SSPL + (g >> 2)) * 4 + (g & 3)) * K;
#pragma unroll
        for (int p = 0; p < K; ++p) topk_insert_v<K>(bd, smp[base + p]);
    }
    tau[q] = fmaxf(bd[K - 1], 0.f);
}

// ---------------- main pass: f16 1-MFMA, 2 query sets/wave, packed (j,d2) store -------
// (R16 shape: QB=128, MB=48 for D=128 / 64 for D=64 — the measured-82us config)
template<int D>
__global__ __launch_bounds__(256)
void knn_main_kernel(const u16* __restrict__ Xh, const float* __restrict__ sqh,
                     const float* __restrict__ tau, const float* __restrict__ sqmax,
                     int* __restrict__ cnt8, int2* __restrict__ cpair, int n, int cps) {
    constexpr int QB = 128;
    constexpr int MB = (D == 128) ? 48 : 64;
    constexpr int NMI = MB / 16;
    constexpr int KS = D / 32, SLOTS = D / 8;
    constexpr int TS = MB * SLOTS, TB = TS * 16, SI = TS / 256;
    constexpr int BUFB = TB + 256;
    __shared__ __align__(16) char smem[2 * BUFB];
    __shared__ int scnt[QB];

    const int tid = threadIdx.x, lane = tid & 63, wid = tid >> 6;
    const int lrow = lane & 15, lhalf = lane >> 4;
    const int q0 = blockIdx.x * QB, sp = blockIdx.y;
    const int rbeg = sp * cps, rend = min(rbeg + cps, n);
    const int nt = (rend - rbeg + MB - 1) / MB;

    const int qA = q0 + wid * 32 + lrow, qB = qA + 16;
    const int qcA = min(qA, n - 1),     qcB = min(qB, n - 1);
    const bool okA = qA < n,            okB = qB < n;
    const int qlocA = wid * 32 + lrow,  qlocB = qlocA + 16;

    half8v qfA[KS], qfB[KS];
#pragma unroll
    for (int ks = 0; ks < KS; ++ks) {
        const int o = (ks * 4 + lhalf) * 8;
        qfA[ks] = *(const half8v*)(Xh + (size_t)qcA * D + o);
        qfB[ks] = *(const half8v*)(Xh + (size_t)qcB * D + o);
    }
    const float sqqA = sqh[qcA], sqqB = sqh[qcB];
    const float sqm = sqmax[0];
    const float eA = err_E(sqqA, sqm), eB = err_E(sqqB, sqm);
    const float rA = sqrtf(tau[qcA]) + 2.f * eA;
    const float rB = sqrtf(tau[qcB]) + 2.f * eB;
    const float tqA = rA * rA + 0.01f;
    const float tqB = rB * rB + 0.01f;

    int srow[SI], soff[SI];
#pragma unroll
    for (int it = 0; it < SI; ++it) {
        const int gs = (it * 4 + wid) * 64 + lane;
        const int row = gs / SLOTS, psl = gs % SLOTS;
        const int ksl = (psl & ~7) | ((psl ^ row) & 7);
        srow[it] = row; soff[it] = ksl * 8;
    }

    auto stage = [&](int t, int b) {
        char* buf = smem + b * BUFB;
        const int row0 = rbeg + t * MB;
#pragma unroll
        for (int it = 0; it < SI; ++it) {
            const int grow = min(row0 + srow[it], rend - 1);
            gld16(Xh + (size_t)grow * D + soff[it], buf + (it * 4 + wid) * 1024);
        }
        if (tid < MB) gld4(sqh + min(row0 + tid, rend - 1), buf + TB);
    };
    auto compute = [&](int t, int b) {
        const char* buf = smem + b * BUFB;
        const u16* hp = (const u16*)buf;
        const float* sql = (const float*)(buf + TB);
        const int row0 = rbeg + t * MB;
        const int rl = rend - row0;
        float4v accA[NMI], accB[NMI];
#pragma unroll
        for (int mi = 0; mi < NMI; ++mi) {
            accA[mi] = (float4v){0.f, 0.f, 0.f, 0.f};
            accB[mi] = (float4v){0.f, 0.f, 0.f, 0.f};
        }
#pragma unroll
        for (int ks = 0; ks < KS; ++ks) {
#pragma unroll
            for (int mi = 0; mi < NMI; ++mi) {
                const int row = mi * 16 + lrow;
                const int ksl = ks * 4 + lhalf;
                const int pk = (ksl & ~7) | ((ksl ^ row) & 7);
                const half8v af = *(const half8v*)(hp + (size_t)row * (SLOTS * 8) + pk * 8);
                accA[mi] = __builtin_amdgcn_mfma_f32_16x16x32_f16(af, qfA[ks], accA[mi], 0, 0, 0);
                accB[mi] = __builtin_amdgcn_mfma_f32_16x16x32_f16(af, qfB[ks], accB[mi], 0, 0, 0);
            }
        }
#pragma unroll
        for (int mi = 0; mi < NMI; ++mi) {
            const float4 s4 = *(const float4*)(sql + mi * 16 + lhalf * 4);
            const float ss[4] = {s4.x, s4.y, s4.z, s4.w};
#pragma unroll
            for (int r = 0; r < 4; ++r) {
                const int dbr = mi * 16 + lhalf * 4 + r;
                const int j = row0 + dbr;
                const bool jok = dbr < rl;
                const float d2A = sqqA + ss[r] - 2.f * accA[mi][r];
                const float d2B = sqqB + ss[r] - 2.f * accB[mi][r];
                if (okA && jok && d2A <= tqA && j != qA) {
                    const int slot = atomicAdd(&scnt[qlocA], 1);   // LDS atomic
                    if (slot < BUDS)
                        cpair[((size_t)sp * n + qA) * BUDS + slot] =
                            make_int2(j, __float_as_int(d2A));
                }
                if (okB && jok && d2B <= tqB && j != qB) {
                    const int slot = atomicAdd(&scnt[qlocB], 1);
                    if (slot < BUDS)
                        cpair[((size_t)sp * n + qB) * BUDS + slot] =
                            make_int2(j, __float_as_int(d2B));
                }
            }
        }
    };

    if (tid < QB) scnt[tid] = 0;
    stage(0, 0);
    __syncthreads();
    for (int t = 0; t < nt; ++t) {
        if (t + 1 < nt) stage(t + 1, (t + 1) & 1);
        compute(t, t & 1);
        __syncthreads();
    }
    if (tid < QB) {
        const int qq = q0 + tid;
        if (qq < n) cnt8[(size_t)sp * n + qq] = scnt[tid];
    }
}

// ---------------- select: screened prefilter + fp32 rescore + gap certificate --------
template<int D, int K>
__global__ __launch_bounds__(256)
void select_kernel(const float* __restrict__ X, const float* __restrict__ sqh,
                   const float* __restrict__ sqmax,
                   const int2* __restrict__ cpair,
                   const int* __restrict__ cnt8, int* __restrict__ idx_out,
                   double* __restrict__ dkth, int* __restrict__ gapok, int n) {
    constexpr int CAP = 128;
    __shared__ int cj[4][BUD];
    __shared__ float cdl[4][BUD];
    __shared__ int cnts[4][NSPLIT];
    __shared__ int sstart[4][NSPLIT + 1];
    __shared__ int rl[4][CAP];
    const int tid = threadIdx.x, lane = tid & 63, w = tid >> 6;
    const int gid = lane >> 4, sub = lane & 15;
    const int q = blockIdx.x * 4 + w;
    const int qc = min(q, n - 1);

    if (lane < NSPLIT)
        cnts[w][lane] = min(cnt8[(size_t)lane * n + qc], BUDS);
    __syncthreads();
    if (lane == 0) {
        int run = 0;
#pragma unroll
        for (int s = 0; s < NSPLIT; ++s) { sstart[w][s] = run; run += cnts[w][s]; }
        sstart[w][NSPLIT] = run;
    }
    __syncthreads();
    const int tot = sstart[w][NSPLIT];

#pragma unroll
    for (int u = 0; u < (BUD + 63) / 64; ++u) {
        const int ci = u * 64 + lane;
        if (ci < tot) {
            int s = 0;
#pragma unroll
            for (int t = 1; t < NSPLIT; ++t) s += (ci >= sstart[w][t]) ? 1 : 0;
            const int slot = ci - sstart[w][s];
            const int2 pr = cpair[((size_t)s * n + qc) * BUDS + slot];
            cj[w][ci] = pr.x;
            cdl[w][ci] = __int_as_float(pr.y);
        }
    }
    __syncthreads();

    // ---- (1) per-lane screened top-K, wave merge -> dK2s + provisional order ----
    float sd[K]; int si_[K];
#pragma unroll
    for (int p = 0; p < K; ++p) { sd[p] = __builtin_inff(); si_[p] = 0x7fffffff; }
#pragma unroll
    for (int u = 0; u < (BUD + 63) / 64; ++u) {
        if (u * 64 < tot) {
            const int ci = u * 64 + lane;
            if (ci < tot) topk_insert_f<K>(sd, si_, cdl[w][ci], cj[w][ci]);
        }
    }
    float dK2s = __builtin_inff();
    int provj[K];
#pragma unroll
    for (int p = 0; p < K; ++p) {
        float md = sd[0]; int mj = si_[0];
#pragma unroll
        for (int u = 1; u < K; ++u)
            if (lexf(sd[u], si_[u], md, mj)) { md = sd[u]; mj = si_[u]; }
#pragma unroll
        for (int off = 32; off >= 1; off >>= 1) {
            const float od = __shfl_xor(md, off, 64);
            const int   oj = __shfl_xor(mj, off, 64);
            if (lexf(od, oj, md, mj)) { md = od; mj = oj; }
        }
        provj[p] = mj;
        if (p == K - 1) dK2s = md;
#pragma unroll
        for (int u = 0; u < K; ++u)
            if (si_[u] == mj) sd[u] = __builtin_inff();
    }

    // ---- (2) rescore window ----
    const float E = err_E(sqh[qc], sqmax[0]);
    const float sk = sqrtf(fmaxf(dK2s, 0.f));
    const float wd = (sk + 2.f * E) * (sk + 2.f * E);

    int rbase = 0;
#pragma unroll
    for (int u = 0; u < (BUD + 63) / 64; ++u) {
        if (u * 64 < tot) {
            const int ci = u * 64 + lane;
            const bool pred = (ci < tot) && (cdl[w][ci] <= wd);
            const unsigned long long mask = __ballot(pred);
            const int offs = (int)__popcll(mask & ((1ull << lane) - 1ull));
            if (pred) {
                const int pos = rbase + offs;
                if (pos < CAP) rl[w][pos] = cj[w][ci];
            }
            rbase += (int)__popcll(mask);
        }
    }
    const int rlc = rbase;

    if (rlc > CAP) {
        if (lane == 0 && q < n) {
#pragma unroll
            for (int p = 0; p < K; ++p) idx_out[(size_t)q * K + p] = provj[p];
            dkth[q] = 1e300;
            gapok[q] = 0;
        }
        return;
    }

    constexpr int FR = D / 64;
    float qa[FR * 4];
#pragma unroll
    for (int f = 0; f < FR; ++f) {
        const float4 a = *(const float4*)(X + (size_t)qc * D + (f * 16 + sub) * 4);
        qa[f * 4 + 0] = a.x; qa[f * 4 + 1] = a.y;
        qa[f * 4 + 2] = a.z; qa[f * 4 + 3] = a.w;
    }

    float bd[K + 1]; int bi[K + 1];
#pragma unroll
    for (int p = 0; p < K + 1; ++p) { bd[p] = __builtin_inff(); bi[p] = 0x7fffffff; }

    for (int base = 0; base < rlc; base += 4) {
        const int ci = base + gid;
        const bool valid = ci < rlc;
        const int j = valid ? rl[w][ci] : 0;
        float acc = 0.f;
#pragma unroll
        for (int f = 0; f < FR; ++f) {
            const float4 b = *(const float4*)(X + (size_t)j * D + (f * 16 + sub) * 4);
            float d;
            d = b.x - qa[f * 4 + 0]; acc = fmaf(d, d, acc);
            d = b.y - qa[f * 4 + 1]; acc = fmaf(d, d, acc);
            d = b.z - qa[f * 4 + 2]; acc = fmaf(d, d, acc);
            d = b.w - qa[f * 4 + 3]; acc = fmaf(d, d, acc);
        }
#pragma unroll
        for (int off = 1; off < 16; off <<= 1)
            acc += __shfl_xor(acc, off, 64);
        const float dd = valid ? acc : __builtin_inff();
        const int   jj = valid ? j : 0x7fffffff;
        topk_insert_f<K + 1>(bd, bi, dd, jj);
    }

    // ---- (3) final merge + certificate ----
    float dK = __builtin_inff(), dK1 = __builtin_inff();
#pragma unroll
    for (int p = 0; p < K + 1; ++p) {
        float md = bd[0]; int mj = bi[0];
#pragma unroll
        for (int u = 1; u < K + 1; ++u)
            if (lexf(bd[u], bi[u], md, mj)) { md = bd[u]; mj = bi[u]; }
#pragma unroll
        for (int off = 32; off >= 1; off >>= 1) {
            const float od = __shfl_xor(md, off, 64);
            const int   oj = __shfl_xor(mj, off, 64);
            if (lexf(od, oj, md, mj)) { md = od; mj = oj; }
        }
        if (p < K && lane == 0 && q < n) idx_out[(size_t)q * K + p] = mj;
        if (p == K - 1) dK = md;
        if (p == K)     dK1 = md;
#pragma unroll
        for (int u = 0; u < K + 1; ++u)
            if (bi[u] == mj) bd[u] = __builtin_inff();
    }

    if (lane == 0 && q < n) {
        const float ek = eps_sel(dK);
        dkth[q] = (double)(dK + ek);
        const float lb = sk + E;                 // outside-window exact-dist LB
        float cutoff = lb * lb;
        if (dK1 < 1e30f) cutoff = fminf(cutoff, dK1 - eps_sel(dK1));
        gapok[q] = (cutoff > dK + ek) ? 1 : 0;
    }
}

// ---------------- certificate check -> flagged-query list ----------------
template<int K>
__global__ void flag_kernel(const int* __restrict__ cnt8, const double* __restrict__ dkth,
                            const float* __restrict__ tau, const float* __restrict__ sqh,
                            const float* __restrict__ sqmax, const int* __restrict__ gapok,
                            int* __restrict__ novf, int* __restrict__ ovf, int n) {
    const int q = blockIdx.x * 256 + threadIdx.x;
    if (q >= n) return;
    const float E = err_E(sqh[q], sqmax[0]);
    const float cv = sqrtf(tau[q]) + E;
    const double certv = (double)cv * (double)cv - 0.01;
    int tot = 0; bool ov = false;
#pragma unroll
    for (int spc = 0; spc < NSPLIT; ++spc) {
        const int c = cnt8[(size_t)spc * n + q];
        tot += c; ov |= (c > BUDS);
    }
    const bool bad = ov || (tot < K) || (dkth[q] > certv) || (gapok[q] == 0);
    if (bad) { const int s = atomicAdd(novf, 1); ovf[s] = q; }
}

// ---------------- parallel exact fallback: per-(query,segment) wave scan --------------
template<int D, int K>
__global__ __launch_bounds__(256)
void fallback_seg_kernel(const float* __restrict__ X, const int* __restrict__ ovf,
                         const int* __restrict__ novf, double* __restrict__ fbd,
                         int* __restrict__ fbi, int n) {
    __shared__ float xq[4][D];
    const int tid = threadIdx.x, lane = tid & 63, w = tid >> 6;
    const int nwave = gridDim.x * 4;
    const int total = min(novf[0], MAXF);
    const int items = total * SEGS;
    const int segsz = (n + SEGS - 1) / SEGS;
    for (int item = blockIdx.x * 4 + w; item < items; item += nwave) {
        const int e = item / SEGS, s = item % SEGS;
        const int q = ovf[e];
        if (lane < D / 4)
            *(float4*)(&xq[w][lane * 4]) = *(const float4*)(X + (size_t)q * D + lane * 4);
        double bd[K]; int bi[K];
#pragma unroll
        for (int p = 0; p < K; ++p) { bd[p] = 1e300; bi[p] = 0x7fffffff; }
        const int rs = s * segsz, re = min(rs + segsz, n);
        for (int r = rs + lane; r < re; r += 64) {
            if (r == q) continue;
            const float4* xr = (const float4*)(X + (size_t)r * D);
            double a0 = 0.0, a1 = 0.0;
#pragma unroll
            for (int t = 0; t < D / 8; ++t) {
                const float4 b0 = xr[2 * t], b1 = xr[2 * t + 1];
                const float4 c0 = *(const float4*)(&xq[w][8 * t]);
                const float4 c1 = *(const float4*)(&xq[w][8 * t + 4]);
                double d;
                d = (double)c0.x - (double)b0.x; a0 = fma(d, d, a0);
                d = (double)c0.y - (double)b0.y; a0 = fma(d, d, a0);
                d = (double)c0.z - (double)b0.z; a0 = fma(d, d, a0);
                d = (double)c0.w - (double)b0.w; a0 = fma(d, d, a0);
                d = (double)c1.x - (double)b1.x; a1 = fma(d, d, a1);
                d = (double)c1.y - (double)b1.y; a1 = fma(d, d, a1);
                d = (double)c1.z - (double)b1.z; a1 = fma(d, d, a1);
                d = (double)c1.w - (double)b1.w; a1 = fma(d, d, a1);
            }
            topk_insert_d<K>(bd, bi, a0 + a1, r);
        }
#pragma unroll
        for (int p = 0; p < K; ++p) {
            double md = bd[0]; int mj = bi[0];
#pragma unroll
            for (int u = 1; u < K; ++u)
                if (lexd(bd[u], bi[u], md, mj)) { md = bd[u]; mj = bi[u]; }
#pragma unroll
            for (int off = 32; off >= 1; off >>= 1) {
                const double od = __shfl_xor(md, off, 64);
                const int    oj = __shfl_xor(mj, off, 64);
                if (lexd(od, oj, md, mj)) { md = od; mj = oj; }
            }
            if (lane == 0) {
                fbd[(size_t)item * K + p] = md;
                fbi[(size_t)item * K + p] = mj;
            }
#pragma unroll
            for (int u = 0; u < K; ++u)
                if (bi[u] == mj) bd[u] = 1e300;
        }
    }
}

// ---------------- merge per-segment partial top-Ks -> final indices ----------------
template<int K>
__global__ __launch_bounds__(256)
void fallback_merge_kernel(const double* __restrict__ fbd, const int* __restrict__ fbi,
                           const int* __restrict__ ovf, const int* __restrict__ novf,
                           int* __restrict__ idx_out, int n) {
    const int tid = threadIdx.x, lane = tid & 63, w = tid >> 6;
    const int nwave = gridDim.x * 4;
    const int total = min(novf[0], MAXF);
    constexpr int E = SEGS * K;
    constexpr int PL = (E + 63) / 64;
    for (int e = blockIdx.x * 4 + w; e < total; e += nwave) {
        const int q = ovf[e];
        double dv[PL]; int jv[PL];
#pragma unroll
        for (int u = 0; u < PL; ++u) {
            const int c = u * 64 + lane;
            if (c < E) { dv[u] = fbd[(size_t)e * E + c]; jv[u] = fbi[(size_t)e * E + c]; }
            else       { dv[u] = 1e300;                  jv[u] = 0x7fffffff; }
        }
#pragma unroll
        for (int p = 0; p < K; ++p) {
            double md = dv[0]; int mj = jv[0];
#pragma unroll
            for (int u = 1; u < PL; ++u)
                if (lexd(dv[u], jv[u], md, mj)) { md = dv[u]; mj = jv[u]; }
#pragma unroll
            for (int off = 32; off >= 1; off >>= 1) {
                const double od = __shfl_xor(md, off, 64);
                const int    oj = __shfl_xor(mj, off, 64);
                if (lexd(od, oj, md, mj)) { md = od; mj = oj; }
            }
            if (lane == 0) idx_out[(size_t)q * K + p] = mj;
#pragma unroll
            for (int u = 0; u < PL; ++u)
                if (jv[u] == mj) dv[u] = 1e300;
        }
    }
}

// ---------------- serial fallback (only for e >= MAXF; never expected) ----------------
template<int D, int K>
__global__ __launch_bounds__(256)
void fallback_kernel(const float* __restrict__ X, const int* __restrict__ ovf,
                     const int* __restrict__ novf, int* __restrict__ idx_out, int n) {
    __shared__ float xq[4][D];
    const int tid = threadIdx.x, lane = tid & 63, w = tid >> 6;
    const int gw = blockIdx.x * 4 + w;
    const int total = novf[0];
    for (int e = MAXF + gw; e < total; e += gridDim.x * 4) {
        const int q = ovf[e];
        if (lane < D / 4)
            *(float4*)(&xq[w][lane * 4]) = *(const float4*)(X + (size_t)q * D + lane * 4);
        double bd[K]; int bi[K];
#pragma unroll
        for (int p = 0; p < K; ++p) { bd[p] = 1e300; bi[p] = 0x7fffffff; }
        for (int r = lane; r < n; r += 64) {
            if (r == q) continue;
            const float4* xr = (const float4*)(X + (size_t)r * D);
            double a0 = 0.0, a1 = 0.0;
#pragma unroll
            for (int t = 0; t < D / 8; ++t) {
                const float4 b0 = xr[2 * t], b1 = xr[2 * t + 1];
                const float4 c0 = *(const float4*)(&xq[w][8 * t]);
                const float4 c1 = *(const float4*)(&xq[w][8 * t + 4]);
                double d;
                d = (double)c0.x - (double)b0.x; a0 = fma(d, d, a0);
                d = (double)c0.y - (double)b0.y; a0 = fma(d, d, a0);
                d = (double)c0.z - (double)b0.z; a0 = fma(d, d, a0);
                d = (double)c0.w - (double)b0.w; a0 = fma(d, d, a0);
                d = (double)c1.x - (double)b1.x; a1 = fma(d, d, a1);
                d = (double)c1.y - (double)b1.y; a1 = fma(d, d, a1);
                d = (double)c1.z - (double)b1.z; a1 = fma(d, d, a1);
                d = (double)c1.w - (double)b1.w; a1 = fma(d, d, a1);
            }
            topk_insert_d<K>(bd, bi, a0 + a1, r);
        }
#pragma unroll
        for (int p = 0; p < K; ++p) {
            double md = bd[0]; int mj = bi[0];
#pragma unroll
            for (int u = 1; u < K; ++u)
                if (lexd(bd[u], bi[u], md, mj)) { md = bd[u]; mj = bi[u]; }
#pragma unroll
            for (int off = 32; off >= 1; off >>= 1) {
                const double od = __shfl_xor(md, off, 64);
                const int    oj = __shfl_xor(mj, off, 64);
                if (lexd(od, oj, md, mj)) { md = od; mj = oj; }
            }
            if (lane == 0) idx_out[(size_t)q * K + p] = mj;
#pragma unroll
            for (int u = 0; u < K; ++u)
                if (bi[u] == mj) bd[u] = 1e300;
        }
    }
}

// ---------------- T = X @ W^T (bias folded into gather-max), PB=32 rows/block ---------
template<int D>
__global__ __launch_bounds__(256)
void lin_kernel(const float* __restrict__ X, const float* __restrict__ W,
                float* __restrict__ T, int n) {
    constexpr int PB = 32;
    __shared__ float Wlds[D * HID];
    __shared__ float Xlds[PB * D];
    const int tid = threadIdx.x;
    const int p0 = blockIdx.x * PB;

    {
        const int h = tid & 127;
        const int hf = tid >> 7;
#pragma unroll
        for (int u = 0; u < D / 8; ++u) {
            const int d0 = hf * (D / 2) + u * 4;
            const float4 v = *(const float4*)(W + (size_t)h * D + d0);
            Wlds[(d0 + 0) * HID + h] = v.x;
            Wlds[(d0 + 1) * HID + h] = v.y;
            Wlds[(d0 + 2) * HID + h] = v.z;
            Wlds[(d0 + 3) * HID + h] = v.w;
        }
    }
    {
        const int rr = tid & 31;
        const int g = tid >> 5;             // 0..7
        constexpr int DG = D / 8;
        const int p = p0 + rr;
        const bool ok = p < n;
#pragma unroll
        for (int u = 0; u < DG / 4; ++u) {
            const int d0 = g * DG + u * 4;
            const float4 v = ok ? *(const float4*)(X + (size_t)p * D + d0)
                                : make_float4(0.f, 0.f, 0.f, 0.f);
            *(float4*)(&Xlds[rr * D + d0]) = v;
        }
    }
    __syncthreads();

    const int pp = tid >> 4;   // 0..15; handles rows pp and pp+16
    const int hh = tid & 15;
    float acc0[8], acc1[8];
#pragma unroll
    for (int e = 0; e < 8; ++e) { acc0[e] = 0.f; acc1[e] = 0.f; }
#pragma unroll 4
    for (int d = 0; d < D; ++d) {
        const float xa0 = Xlds[pp * D + d];
        const float xa1 = Xlds[(pp + 16) * D + d];
#pragma unroll
        for (int e = 0; e < 8; ++e) {
            const float wv = Wlds[d * HID + hh + 16 * e];
            acc0[e] = fmaf(xa0, wv, acc0[e]);
            acc1[e] = fmaf(xa1, wv, acc1[e]);
        }
    }
    const int pA = p0 + pp, pB = p0 + pp + 16;
    if (pA < n) {
#pragma unroll
        for (int e = 0; e < 8; ++e)
            T[(size_t)pA * HID + hh + 16 * e] = acc0[e];
    }
    if (pB < n) {
#pragma unroll
        for (int e = 0; e < 8; ++e)
            T[(size_t)pB * HID + hh + 16 * e] = acc1[e];
    }
}

// ---------------- h[i,:] = max_j T[idx_j,:] - T[i,:] + b ----------------
template<int K>
__global__ void gathermax_kernel(const float* __restrict__ T, const int* __restrict__ idx,
                                 const float* __restrict__ b, float* __restrict__ out, int n) {
    const int i = blockIdx.x;
    const int h = threadIdx.x;
    float m = -__builtin_inff();
#pragma unroll
    for (int t = 0; t < K; ++t) {
        const int j = idx[(size_t)i * K + t];
        m = fmaxf(m, T[(size_t)j * HID + h]);
    }
    out[(size_t)i * HID + h] = m - T[(size_t)i * HID + h] + b[h];
}

// ---------------- out = h2 @ Wl^T + bl ----------------
__global__ void final_kernel(const float* __restrict__ h2, const float* __restrict__ Wl,
                             const float* __restrict__ bl, float* __restrict__ out, int n) {
    const int t = blockIdx.x * 256 + threadIdx.x;
    const int i = t >> 4;
    const int c = t & 15;
    if (i >= n || c >= 10) return;
    const float* hr = h2 + (size_t)i * HID;
    const float* wr = Wl + (size_t)c * HID;
    float s = 0.f;
#pragma unroll 4
    for (int d = 0; d < HID; ++d) s = fmaf(hr[d], wr[d], s);
    out[(size_t)i * 10 + c] = s + bl[c];
}

extern "C" void kernel_launch(void* const* d_in, const int* in_sizes, int n_in,
                              void* d_out, int out_size, void* d_ws, size_t ws_size,
                              hipStream_t stream) {
    const float* x  = (const float*)d_in[0];
    const float* W1 = (const float*)d_in[1];
    const float* b1 = (const float*)d_in[2];
    const float* W2 = (const float*)d_in[3];
    const float* b2 = (const float*)d_in[4];
    const float* Wl = (const float*)d_in[5];
    const float* bl = (const float*)d_in[6];
    float* out = (float*)d_out;
    const int n = in_sizes[0] / 64;   // 10000
    constexpr int K1 = 5, K2 = 10;

    char* ws = (char*)d_ws;
    size_t off = 0;
    auto alloc = [&](size_t bytes) -> void* {
        void* p = ws + off;
        off = (off + bytes + 255) & ~(size_t)255;
        return p;
    };
    // union region with disjoint lifetimes (knn / fallback / lin phases)
    const size_t cpairB = (size_t)NSPLIT * n * BUDS * 8;         // 30.7 MB
    const size_t smpB   = (size_t)n * SSPL * 4 * K2 * 4;         // 12.8 MB
    const size_t fbdB   = (size_t)MAXF * SEGS * K2 * 8;          // 5.24 MB
    const size_t fbiB   = (size_t)MAXF * SEGS * K2 * 4;          // 2.62 MB
    const size_t TB_    = (size_t)n * HID * 4;                   // 5.12 MB
    size_t regB = cpairB + smpB;
    if (fbdB + fbiB > regB) regB = fbdB + fbiB;
    if (TB_ > regB) regB = TB_;
    char*  region = (char*)alloc(regB);
    float* T1    = (float*)region;
    int2*  cpair = (int2*)region;
    float* smp   = (float*)(region + cpairB);
    double* fbd  = (double*)region;
    int*   fbi   = (int*)(region + fbdB);
    float* h1b  = (float*)alloc((size_t)n * HID * 4);
    float* sqh  = (float*)alloc((size_t)n * 4);
    int*   idx1 = (int*)alloc((size_t)n * K1 * 4);
    int*   idx2 = (int*)alloc((size_t)n * K2 * 4);
    u16*   Xh   = (u16*)alloc((size_t)n * 64 * 2);
    u16*   Hh   = (u16*)alloc((size_t)n * HID * 2);
    float* tau  = (float*)alloc((size_t)n * 4);
    int*   cnt8 = (int*)alloc((size_t)NSPLIT * n * 4);
    double* dkth = (double*)alloc((size_t)n * 8);
    int*   gok  = (int*)alloc((size_t)n * 4);
    int*   ovf  = (int*)alloc((size_t)n * 4);
    int*   novf = (int*)alloc(256);
    float* sqmax = (float*)alloc(256);
    float* T2  = T1;
    float* h2b = h1b;

    const int cps  = (n + NSPLIT - 1) / NSPLIT;   // 625
    const int qbs  = (n + 63) / 64;               // 157 (sample pass)
    const int qbs2 = (n + 127) / 128;             // 79  (main pass, QB=128)
    const int sstr = n / SMP;                     // 4
    const int nb   = (n + 255) / 256;

    // ---- layer 1 (D=64, K=5) ----
    zero_misc_kernel<<<1, 64, 0, stream>>>(novf, sqmax);
    conv_f16_kernel<64><<<nb, 256, 0, stream>>>(x, Xh, sqh, sqmax, n);
    sample_knn_kernel<64, K1><<<dim3(qbs, SSPL), 256, 0, stream>>>(Xh, sqh, smp, n, sstr);
    tau_merge_kernel<K1><<<nb, 256, 0, stream>>>(smp, tau, n);
    knn_main_kernel<64><<<dim3(qbs2, NSPLIT), 256, 0, stream>>>(Xh, sqh, tau, sqmax, cnt8, cpair, n, cps);
    select_kernel<64, K1><<<(n + 3) / 4, 256, 0, stream>>>(x, sqh, sqmax, cpair, cnt8, idx1, dkth, gok, n);
    flag_kernel<K1><<<nb, 256, 0, stream>>>(cnt8, dkth, tau, sqh, sqmax, gok, novf, ovf, n);
    fallback_seg_kernel<64, K1><<<1024, 256, 0, stream>>>(x, ovf, novf, fbd, fbi, n);
    fallback_merge_kernel<K1><<<256, 256, 0, stream>>>(fbd, fbi, ovf, novf, idx1, n);
    fallback_kernel<64, K1><<<256, 256, 0, stream>>>(x, ovf, novf, idx1, n);
    lin_kernel<64><<<(n + 31) / 32, 256, 0, stream>>>(x, W1, T1, n);
    gathermax_kernel<K1><<<n, HID, 0, stream>>>(T1, idx1, b1, h1b, n);

    // ---- layer 2 (D=128, K=10) ----
    zero_misc_kernel<<<1, 64, 0, stream>>>(novf, sqmax);
    conv_f16_kernel<HID><<<nb, 256, 0, stream>>>(h1b, Hh, sqh, sqmax, n);
    sample_knn_kernel<HID, K2><<<dim3(qbs, SSPL), 256, 0, stream>>>(Hh, sqh, smp, n, sstr);
    tau_merge_kernel<K2><<<nb, 256, 0, stream>>>(smp, tau, n);
    knn_main_kernel<HID><<<dim3(qbs2, NSPLIT), 256, 0, stream>>>(Hh, sqh, tau, sqmax, cnt8, cpair, n, cps);
    select_kernel<HID, K2><<<(n + 3) / 4, 256, 0, stream>>>(h1b, sqh, sqmax, cpair, cnt8, idx2, dkth, gok, n);
    flag_kernel<K2><<<nb, 256, 0, stream>>>(cnt8, dkth, tau, sqh, sqmax, gok, novf, ovf, n);
    fallback_seg_kernel<HID, K2><<<1024, 256, 0, stream>>>(h1b, ovf, novf, fbd, fbi, n);
    fallback_merge_kernel<K2><<<256, 256, 0, stream>>>(fbd, fbi, ovf, novf, idx2, n);
    fallback_kernel<HID, K2><<<256, 256, 0, stream>>>(h1b, ovf, novf, idx2, n);
    lin_kernel<HID><<<(n + 31) / 32, 256, 0, stream>>>(h1b, W2, T2, n);
    gathermax_kernel<K2><<<n, HID, 0, stream>>>(T2, idx2, b2, h2b, n);

    // ---- head ----
    final_kernel<<<(n * 16 + 255) / 256, 256, 0, stream>>>(h2b, Wl, bl, out, n);
}

// Round 20
// 466.103 us; speedup vs baseline: 1.0624x; 1.0624x over previous
//
#include <hip/hip_runtime.h>

#define DEVINLINE __device__ __forceinline__

typedef unsigned short u16;
typedef _Float16 f16;
typedef __attribute__((ext_vector_type(8))) _Float16 half8v;
typedef __attribute__((ext_vector_type(4))) float float4v;

constexpr int HID = 128;
constexpr int NSPLIT = 16;    // main-pass column splits
constexpr int BUDS = 24;      // candidate budget per (split, query)
constexpr int BUD = NSPLIT * BUDS;   // 384 total select capacity
constexpr int SMP = 1024;     // sample size for tau
constexpr int SSPL = 4;       // sample row-splits (grid parallelism)
constexpr int SEGS = 32;      // fallback scan segments per query
constexpr int MAXF = 2048;    // fast-fallback capacity (scratch-sized)

// ---------- small helpers ----------
DEVINLINE void gld16(const void* g, void* l) {
    __builtin_amdgcn_global_load_lds((const __attribute__((address_space(1))) unsigned int*)g,
                                     (__attribute__((address_space(3))) unsigned int*)l, 16, 0, 0);
}
DEVINLINE void gld4(const void* g, void* l) {
    __builtin_amdgcn_global_load_lds((const __attribute__((address_space(1))) unsigned int*)g,
                                     (__attribute__((address_space(3))) unsigned int*)l, 4, 0, 0);
}
// rigorous |d - d~| (distance units) bound for f16 screening metric
DEVINLINE float err_E(float sqq, float sqm) {
    return 6.2e-4f * (sqrtf(sqq) + sqrtf(sqm)) + 0.02f;
}
// rigorous |fp32_d2 - exact_d2| bound for the select rescore
DEVINLINE float eps_sel(float d) { return 2e-6f * (d + 1.f); }
// ascending value-only top-K list (static indices)
template<int K>
DEVINLINE void topk_insert_v(float (&bd)[K], float d) {
    if (d >= bd[K - 1]) return;
#pragma unroll
    for (int p = 0; p < K; ++p) {
        const float mn = fminf(d, bd[p]);
        const float mx = fmaxf(d, bd[p]);
        bd[p] = mn; d = mx;
    }
}
DEVINLINE bool lexd(double d1, int i1, double d2, int i2) {
    return (d1 < d2) || ((d1 == d2) && (i1 < i2));
}
DEVINLINE bool lexf(float d1, int i1, float d2, int i2) {
    return (d1 < d2) || ((d1 == d2) && (i1 < i2));
}
template<int K>
DEVINLINE void topk_insert_d(double (&bd)[K], int (&bi)[K], double d, int j) {
    if (!lexd(d, j, bd[K - 1], bi[K - 1])) return;
    double cd = d; int ci = j;
#pragma unroll
    for (int p = 0; p < K; ++p) {
        const bool lt = lexd(cd, ci, bd[p], bi[p]);
        const double sd = bd[p]; const int si = bi[p];
        bd[p] = lt ? cd : sd;  bi[p] = lt ? ci : si;
        cd = lt ? sd : cd;     ci = lt ? si : ci;
    }
}
template<int K>
DEVINLINE void topk_insert_f(float (&bd)[K], int (&bi)[K], float d, int j) {
    if (!lexf(d, j, bd[K - 1], bi[K - 1])) return;
    float cd = d; int ci = j;
#pragma unroll
    for (int p = 0; p < K; ++p) {
        const bool lt = lexf(cd, ci, bd[p], bi[p]);
        const float sd = bd[p]; const int si = bi[p];
        bd[p] = lt ? cd : sd;  bi[p] = lt ? ci : si;
        cd = lt ? sd : cd;     ci = lt ? si : ci;
    }
}

// ---------------- per-layer init ----------------
__global__ void zero_misc_kernel(int* __restrict__ novf, float* __restrict__ sqmax) {
    if (blockIdx.x == 0 && threadIdx.x == 0) { novf[0] = 0; *(int*)sqmax = 0; }
}

// ---------------- fp32 -> fp16 plane + f16 norms ----------------
template<int D>
__global__ void conv_f16_kernel(const float* __restrict__ X, u16* __restrict__ Xh,
                                float* __restrict__ sqh, float* __restrict__ sqmax, int n) {
    const int i = blockIdx.x * 256 + threadIdx.x;
    float s = 0.f;
    if (i < n) {
        const float4* row = (const float4*)(X + (size_t)i * D);
        ushort4* dst = (ushort4*)(Xh + (size_t)i * D);
#pragma unroll
        for (int u = 0; u < D / 4; ++u) {
            const float4 v = row[u];
            const f16 h0 = (f16)v.x, h1 = (f16)v.y, h2 = (f16)v.z, h3 = (f16)v.w;
            const float f0 = (float)h0, f1 = (float)h1, f2 = (float)h2, f3 = (float)h3;
            s += f0 * f0 + f1 * f1 + f2 * f2 + f3 * f3;
            ushort4 o = {__builtin_bit_cast(u16, h0), __builtin_bit_cast(u16, h1),
                         __builtin_bit_cast(u16, h2), __builtin_bit_cast(u16, h3)};
            dst[u] = o;
        }
        sqh[i] = s;
    }
    float m = (i < n) ? s : 0.f;
#pragma unroll
    for (int off = 32; off >= 1; off >>= 1) m = fmaxf(m, __shfl_xor(m, off, 64));
    if ((threadIdx.x & 63) == 0) atomicMax((int*)sqmax, __float_as_int(m));
}

// ---------------- sample pass: row-split x SSPL, exact-f16-metric top-K ----------------
template<int D, int K>
__global__ __launch_bounds__(256)
void sample_knn_kernel(const u16* __restrict__ Xh, const float* __restrict__ sqh,
                       float* __restrict__ smp, int n, int sstr) {
    constexpr int MB = 64, NMI = 4;
    constexpr int KS = D / 32, SLOTS = D / 8;
    constexpr int TS = MB * SLOTS, TB = TS * 16, SI = TS / 256;
    constexpr int BUFB = TB + 256;
    constexpr int SROWS = SMP / SSPL;   // 256
    constexpr int NT = SROWS / MB;      // 4
    __shared__ __align__(16) char smem[2 * BUFB];

    const int tid = threadIdx.x, lane = tid & 63, wid = tid >> 6;
    const int lrow = lane & 15, lhalf = lane >> 4;
    const int q0 = blockIdx.x * 64, sp = blockIdx.y;
    const int sbeg = sp * SROWS;
    const int q = q0 + wid * 16 + lrow, qc = min(q, n - 1);

    half8v qf[KS];
#pragma unroll
    for (int ks = 0; ks < KS; ++ks)
        qf[ks] = *(const half8v*)(Xh + (size_t)qc * D + (ks * 4 + lhalf) * 8);
    const float sqq = sqh[qc];

    int srow[SI], soff[SI];
#pragma unroll
    for (int it = 0; it < SI; ++it) {
        const int gs = (it * 4 + wid) * 64 + lane;
        const int row = gs / SLOTS, psl = gs % SLOTS;
        const int ksl = (psl & ~7) | ((psl ^ row) & 7);
        srow[it] = row; soff[it] = ksl * 8;
    }

    float bd[K];
#pragma unroll
    for (int p = 0; p < K; ++p) bd[p] = __builtin_inff();

    auto stage = [&](int t, int b) {
        char* buf = smem + b * BUFB;
        const int s0 = sbeg + t * MB;
#pragma unroll
        for (int it = 0; it < SI; ++it) {
            const size_t phys = (size_t)(s0 + srow[it]) * sstr;
            gld16(Xh + phys * D + soff[it], buf + (it * 4 + wid) * 1024);
        }
        if (wid == 0) gld4(sqh + (size_t)(s0 + lane) * sstr, buf + TB);
    };
    auto compute = [&](int t, int b) {
        const char* buf = smem + b * BUFB;
        const u16* hp = (const u16*)buf;
        const float* sql = (const float*)(buf + TB);
        const int s0 = sbeg + t * MB;
        float4v acc[NMI];
#pragma unroll
        for (int mi = 0; mi < NMI; ++mi) acc[mi] = (float4v){0.f, 0.f, 0.f, 0.f};
#pragma unroll
        for (int ks = 0; ks < KS; ++ks) {
#pragma unroll
            for (int mi = 0; mi < NMI; ++mi) {
                const int row = mi * 16 + lrow;
                const int ksl = ks * 4 + lhalf;
                const int pk = (ksl & ~7) | ((ksl ^ row) & 7);
                const half8v af = *(const half8v*)(hp + (size_t)row * (SLOTS * 8) + pk * 8);
                acc[mi] = __builtin_amdgcn_mfma_f32_16x16x32_f16(af, qf[ks], acc[mi], 0, 0, 0);
            }
        }
#pragma unroll
        for (int mi = 0; mi < NMI; ++mi) {
            const float4 s4 = *(const float4*)(sql + mi * 16 + lhalf * 4);
            const float ss[4] = {s4.x, s4.y, s4.z, s4.w};
#pragma unroll
            for (int r = 0; r < 4; ++r) {
                const int sidx = s0 + mi * 16 + lhalf * 4 + r;
                const int j = sidx * sstr;
                const float d2 = sqq + ss[r] - 2.f * acc[mi][r];
                if (j != q) topk_insert_v<K>(bd, d2);
            }
        }
    };

    stage(0, 0);
    __syncthreads();
    for (int t = 0; t < NT; ++t) {
        if (t + 1 < NT) stage(t + 1, (t + 1) & 1);
        compute(t, t & 1);
        __syncthreads();
    }

    if (q < n) {
        const size_t base = ((size_t)(q * SSPL + sp) * 4 + lhalf) * K;
#pragma unroll
        for (int p = 0; p < K; ++p) smp[base + p] = bd[p];
    }
}

// ---------------- merge sample lists -> raw s~ (kth sample screened d2) ----------------
template<int K>
__global__ void tau_merge_kernel(const float* __restrict__ smp, float* __restrict__ tau, int n) {
    const int q = blockIdx.x * 256 + threadIdx.x;
    if (q >= n) return;
    float bd[K];
#pragma unroll
    for (int p = 0; p < K; ++p) bd[p] = __builtin_inff();
    for (int g = 0; g < SSPL * 4; ++g) {
        const size_t base = ((size_t)(q * SSPL + (g >> 2)) * 4 + (g & 3)) * K;
#pragma unroll
        for (int p = 0; p < K; ++p) topk_insert_v<K>(bd, smp[base + p]);
    }
    tau[q] = fmaxf(bd[K - 1], 0.f);
}

// ---------------- main pass: f16 1-MFMA, 2 query sets/wave, packed (j,d2) store -------
// (R16 shape: QB=128, MB=48 for D=128 / 64 for D=64 — the measured-82us config)
template<int D>
__global__ __launch_bounds__(256)
void knn_main_kernel(const u16* __restrict__ Xh, const float* __restrict__ sqh,
                     const float* __restrict__ tau, const float* __restrict__ sqmax,
                     int* __restrict__ cnt8, int2* __restrict__ cpair, int n, int cps) {
    constexpr int QB = 128;
    constexpr int MB = (D == 128) ? 48 : 64;
    constexpr int NMI = MB / 16;
    constexpr int KS = D / 32, SLOTS = D / 8;
    constexpr int TS = MB * SLOTS, TB = TS * 16, SI = TS / 256;
    constexpr int BUFB = TB + 256;
    __shared__ __align__(16) char smem[2 * BUFB];
    __shared__ int scnt[QB];

    const int tid = threadIdx.x, lane = tid & 63, wid = tid >> 6;
    const int lrow = lane & 15, lhalf = lane >> 4;
    const int q0 = blockIdx.x * QB, sp = blockIdx.y;
    const int rbeg = sp * cps, rend = min(rbeg + cps, n);
    const int nt = (rend - rbeg + MB - 1) / MB;

    const int qA = q0 + wid * 32 + lrow, qB = qA + 16;
    const int qcA = min(qA, n - 1),     qcB = min(qB, n - 1);
    const bool okA = qA < n,            okB = qB < n;
    const int qlocA = wid * 32 + lrow,  qlocB = qlocA + 16;

    half8v qfA[KS], qfB[KS];
#pragma unroll
    for (int ks = 0; ks < KS; ++ks) {
        const int o = (ks * 4 + lhalf) * 8;
        qfA[ks] = *(const half8v*)(Xh + (size_t)qcA * D + o);
        qfB[ks] = *(const half8v*)(Xh + (size_t)qcB * D + o);
    }
    const float sqqA = sqh[qcA], sqqB = sqh[qcB];
    const float sqm = sqmax[0];
    const float eA = err_E(sqqA, sqm), eB = err_E(sqqB, sqm);
    const float rA = sqrtf(tau[qcA]) + 2.f * eA;
    const float rB = sqrtf(tau[qcB]) + 2.f * eB;
    const float tqA = rA * rA + 0.01f;
    const float tqB = rB * rB + 0.01f;

    int srow[SI], soff[SI];
#pragma unroll
    for (int it = 0; it < SI; ++it) {
        const int gs = (it * 4 + wid) * 64 + lane;
        const int row = gs / SLOTS, psl = gs % SLOTS;
        const int ksl = (psl & ~7) | ((psl ^ row) & 7);
        srow[it] = row; soff[it] = ksl * 8;
    }

    auto stage = [&](int t, int b) {
        char* buf = smem + b * BUFB;
        const int row0 = rbeg + t * MB;
#pragma unroll
        for (int it = 0; it < SI; ++it) {
            const int grow = min(row0 + srow[it], rend - 1);
            gld16(Xh + (size_t)grow * D + soff[it], buf + (it * 4 + wid) * 1024);
        }
        if (tid < MB) gld4(sqh + min(row0 + tid, rend - 1), buf + TB);
    };
    auto compute = [&](int t, int b) {
        const char* buf = smem + b * BUFB;
        const u16* hp = (const u16*)buf;
        const float* sql = (const float*)(buf + TB);
        const int row0 = rbeg + t * MB;
        const int rl = rend - row0;
        float4v accA[NMI], accB[NMI];
#pragma unroll
        for (int mi = 0; mi < NMI; ++mi) {
            accA[mi] = (float4v){0.f, 0.f, 0.f, 0.f};
            accB[mi] = (float4v){0.f, 0.f, 0.f, 0.f};
        }
#pragma unroll
        for (int ks = 0; ks < KS; ++ks) {
#pragma unroll
            for (int mi = 0; mi < NMI; ++mi) {
                const int row = mi * 16 + lrow;
                const int ksl = ks * 4 + lhalf;
                const int pk = (ksl & ~7) | ((ksl ^ row) & 7);
                const half8v af = *(const half8v*)(hp + (size_t)row * (SLOTS * 8) + pk * 8);
                accA[mi] = __builtin_amdgcn_mfma_f32_16x16x32_f16(af, qfA[ks], accA[mi], 0, 0, 0);
                accB[mi] = __builtin_amdgcn_mfma_f32_16x16x32_f16(af, qfB[ks], accB[mi], 0, 0, 0);
            }
        }
#pragma unroll
        for (int mi = 0; mi < NMI; ++mi) {
            const float4 s4 = *(const float4*)(sql + mi * 16 + lhalf * 4);
            const float ss[4] = {s4.x, s4.y, s4.z, s4.w};
#pragma unroll
            for (int r = 0; r < 4; ++r) {
                const int dbr = mi * 16 + lhalf * 4 + r;
                const int j = row0 + dbr;
                const bool jok = dbr < rl;
                const float d2A = sqqA + ss[r] - 2.f * accA[mi][r];
                const float d2B = sqqB + ss[r] - 2.f * accB[mi][r];
                if (okA && jok && d2A <= tqA && j != qA) {
                    const int slot = atomicAdd(&scnt[qlocA], 1);   // LDS atomic
                    if (slot < BUDS)
                        cpair[((size_t)sp * n + qA) * BUDS + slot] =
                            make_int2(j, __float_as_int(d2A));
                }
                if (okB && jok && d2B <= tqB && j != qB) {
                    const int slot = atomicAdd(&scnt[qlocB], 1);
                    if (slot < BUDS)
                        cpair[((size_t)sp * n + qB) * BUDS + slot] =
                            make_int2(j, __float_as_int(d2B));
                }
            }
        }
    };

    if (tid < QB) scnt[tid] = 0;
    stage(0, 0);
    __syncthreads();
    for (int t = 0; t < nt; ++t) {
        if (t + 1 < nt) stage(t + 1, (t + 1) & 1);
        compute(t, t & 1);
        __syncthreads();
    }
    if (tid < QB) {
        const int qq = q0 + tid;
        if (qq < n) cnt8[(size_t)sp * n + qq] = scnt[tid];
    }
}

// ---------------- select: screened prefilter + fp32 rescore + gap certificate --------
template<int D, int K>
__global__ __launch_bounds__(256)
void select_kernel(const float* __restrict__ X, const float* __restrict__ sqh,
                   const float* __restrict__ sqmax,
                   const int2* __restrict__ cpair,
                   const int* __restrict__ cnt8, int* __restrict__ idx_out,
                   double* __restrict__ dkth, int* __restrict__ gapok, int n) {
    constexpr int CAP = 128;
    __shared__ int cj[4][BUD];
    __shared__ float cdl[4][BUD];
    __shared__ int cnts[4][NSPLIT];
    __shared__ int sstart[4][NSPLIT + 1];
    __shared__ int rl[4][CAP];
    const int tid = threadIdx.x, lane = tid & 63, w = tid >> 6;
    const int gid = lane >> 4, sub = lane & 15;
    const int q = blockIdx.x * 4 + w;
    const int qc = min(q, n - 1);

    if (lane < NSPLIT)
        cnts[w][lane] = min(cnt8[(size_t)lane * n + qc], BUDS);
    __syncthreads();
    if (lane == 0) {
        int run = 0;
#pragma unroll
        for (int s = 0; s < NSPLIT; ++s) { sstart[w][s] = run; run += cnts[w][s]; }
        sstart[w][NSPLIT] = run;
    }
    __syncthreads();
    const int tot = sstart[w][NSPLIT];

#pragma unroll
    for (int u = 0; u < (BUD + 63) / 64; ++u) {
        const int ci = u * 64 + lane;
        if (ci < tot) {
            int s = 0;
#pragma unroll
            for (int t = 1; t < NSPLIT; ++t) s += (ci >= sstart[w][t]) ? 1 : 0;
            const int slot = ci - sstart[w][s];
            const int2 pr = cpair[((size_t)s * n + qc) * BUDS + slot];
            cj[w][ci] = pr.x;
            cdl[w][ci] = __int_as_float(pr.y);
        }
    }
    __syncthreads();

    // ---- (1) per-lane screened top-K, wave merge -> dK2s + provisional order ----
    float sd[K]; int si_[K];
#pragma unroll
    for (int p = 0; p < K; ++p) { sd[p] = __builtin_inff(); si_[p] = 0x7fffffff; }
#pragma unroll
    for (int u = 0; u < (BUD + 63) / 64; ++u) {
        if (u * 64 < tot) {
            const int ci = u * 64 + lane;
            if (ci < tot) topk_insert_f<K>(sd, si_, cdl[w][ci], cj[w][ci]);
        }
    }
    float dK2s = __builtin_inff();
    int provj[K];
#pragma unroll
    for (int p = 0; p < K; ++p) {
        float md = sd[0]; int mj = si_[0];
#pragma unroll
        for (int u = 1; u < K; ++u)
            if (lexf(sd[u], si_[u], md, mj)) { md = sd[u]; mj = si_[u]; }
#pragma unroll
        for (int off = 32; off >= 1; off >>= 1) {
            const float od = __shfl_xor(md, off, 64);
            const int   oj = __shfl_xor(mj, off, 64);
            if (lexf(od, oj, md, mj)) { md = od; mj = oj; }
        }
        provj[p] = mj;
        if (p == K - 1) dK2s = md;
#pragma unroll
        for (int u = 0; u < K; ++u)
            if (si_[u] == mj) sd[u] = __builtin_inff();
    }

    // ---- (2) rescore window ----
    const float E = err_E(sqh[qc], sqmax[0]);
    const float sk = sqrtf(fmaxf(dK2s, 0.f));
    const float wd = (sk + 2.f * E) * (sk + 2.f * E);

    int rbase = 0;
#pragma unroll
    for (int u = 0; u < (BUD + 63) / 64; ++u) {
        if (u * 64 < tot) {
            const int ci = u * 64 + lane;
            const bool pred = (ci < tot) && (cdl[w][ci] <= wd);
            const unsigned long long mask = __ballot(pred);
            const int offs = (int)__popcll(mask & ((1ull << lane) - 1ull));
            if (pred) {
                const int pos = rbase + offs;
                if (pos < CAP) rl[w][pos] = cj[w][ci];
            }
            rbase += (int)__popcll(mask);
        }
    }
    const int rlc = rbase;

    if (rlc > CAP) {
        if (lane == 0 && q < n) {
#pragma unroll
            for (int p = 0; p < K; ++p) idx_out[(size_t)q * K + p] = provj[p];
            dkth[q] = 1e300;
            gapok[q] = 0;
        }
        return;
    }

    constexpr int FR = D / 64;
    float qa[FR * 4];
#pragma unroll
    for (int f = 0; f < FR; ++f) {
        const float4 a = *(const float4*)(X + (size_t)qc * D + (f * 16 + sub) * 4);
        qa[f * 4 + 0] = a.x; qa[f * 4 + 1] = a.y;
        qa[f * 4 + 2] = a.z; qa[f * 4 + 3] = a.w;
    }

    float bd[K + 1]; int bi[K + 1];
#pragma unroll
    for (int p = 0; p < K + 1; ++p) { bd[p] = __builtin_inff(); bi[p] = 0x7fffffff; }

    for (int base = 0; base < rlc; base += 4) {
        const int ci = base + gid;
        const bool valid = ci < rlc;
        const int j = valid ? rl[w][ci] : 0;
        float acc = 0.f;
#pragma unroll
        for (int f = 0; f < FR; ++f) {
            const float4 b = *(const float4*)(X + (size_t)j * D + (f * 16 + sub) * 4);
            float d;
            d = b.x - qa[f * 4 + 0]; acc = fmaf(d, d, acc);
            d = b.y - qa[f * 4 + 1]; acc = fmaf(d, d, acc);
            d = b.z - qa[f * 4 + 2]; acc = fmaf(d, d, acc);
            d = b.w - qa[f * 4 + 3]; acc = fmaf(d, d, acc);
        }
#pragma unroll
        for (int off = 1; off < 16; off <<= 1)
            acc += __shfl_xor(acc, off, 64);
        const float dd = valid ? acc : __builtin_inff();
        const int   jj = valid ? j : 0x7fffffff;
        topk_insert_f<K + 1>(bd, bi, dd, jj);
    }

    // ---- (3) final merge + certificate ----
    float dK = __builtin_inff(), dK1 = __builtin_inff();
#pragma unroll
    for (int p = 0; p < K + 1; ++p) {
        float md = bd[0]; int mj = bi[0];
#pragma unroll
        for (int u = 1; u < K + 1; ++u)
            if (lexf(bd[u], bi[u], md, mj)) { md = bd[u]; mj = bi[u]; }
#pragma unroll
        for (int off = 32; off >= 1; off >>= 1) {
            const float od = __shfl_xor(md, off, 64);
            const int   oj = __shfl_xor(mj, off, 64);
            if (lexf(od, oj, md, mj)) { md = od; mj = oj; }
        }
        if (p < K && lane == 0 && q < n) idx_out[(size_t)q * K + p] = mj;
        if (p == K - 1) dK = md;
        if (p == K)     dK1 = md;
#pragma unroll
        for (int u = 0; u < K + 1; ++u)
            if (bi[u] == mj) bd[u] = __builtin_inff();
    }

    if (lane == 0 && q < n) {
        const float ek = eps_sel(dK);
        dkth[q] = (double)(dK + ek);
        const float lb = sk + E;                 // outside-window exact-dist LB
        float cutoff = lb * lb;
        if (dK1 < 1e30f) cutoff = fminf(cutoff, dK1 - eps_sel(dK1));
        gapok[q] = (cutoff > dK + ek) ? 1 : 0;
    }
}

// ---------------- certificate check -> flagged-query list ----------------
template<int K>
__global__ void flag_kernel(const int* __restrict__ cnt8, const double* __restrict__ dkth,
                            const float* __restrict__ tau, const float* __restrict__ sqh,
                            const float* __restrict__ sqmax, const int* __restrict__ gapok,
                            int* __restrict__ novf, int* __restrict__ ovf, int n) {
    const int q = blockIdx.x * 256 + threadIdx.x;
    if (q >= n) return;
    const float E = err_E(sqh[q], sqmax[0]);
    const float cv = sqrtf(tau[q]) + E;
    const double certv = (double)cv * (double)cv - 0.01;
    int tot = 0; bool ov = false;
#pragma unroll
    for (int spc = 0; spc < NSPLIT; ++spc) {
        const int c = cnt8[(size_t)spc * n + q];
        tot += c; ov |= (c > BUDS);
    }
    const bool bad = ov || (tot < K) || (dkth[q] > certv) || (gapok[q] == 0);
    if (bad) { const int s = atomicAdd(novf, 1); ovf[s] = q; }
}

// ---------------- parallel exact fallback: per-(query,segment) wave scan --------------
template<int D, int K>
__global__ __launch_bounds__(256)
void fallback_seg_kernel(const float* __restrict__ X, const int* __restrict__ ovf,
                         const int* __restrict__ novf, double* __restrict__ fbd,
                         int* __restrict__ fbi, int n) {
    __shared__ float xq[4][D];
    const int tid = threadIdx.x, lane = tid & 63, w = tid >> 6;
    const int nwave = gridDim.x * 4;
    const int total = min(novf[0], MAXF);
    const int items = total * SEGS;
    const int segsz = (n + SEGS - 1) / SEGS;
    for (int item = blockIdx.x * 4 + w; item < items; item += nwave) {
        const int e = item / SEGS, s = item % SEGS;
        const int q = ovf[e];
        if (lane < D / 4)
            *(float4*)(&xq[w][lane * 4]) = *(const float4*)(X + (size_t)q * D + lane * 4);
        double bd[K]; int bi[K];
#pragma unroll
        for (int p = 0; p < K; ++p) { bd[p] = 1e300; bi[p] = 0x7fffffff; }
        const int rs = s * segsz, re = min(rs + segsz, n);
        for (int r = rs + lane; r < re; r += 64) {
            if (r == q) continue;
            const float4* xr = (const float4*)(X + (size_t)r * D);
            double a0 = 0.0, a1 = 0.0;
#pragma unroll
            for (int t = 0; t < D / 8; ++t) {
                const float4 b0 = xr[2 * t], b1 = xr[2 * t + 1];
                const float4 c0 = *(const float4*)(&xq[w][8 * t]);
                const float4 c1 = *(const float4*)(&xq[w][8 * t + 4]);
                double d;
                d = (double)c0.x - (double)b0.x; a0 = fma(d, d, a0);
                d = (double)c0.y - (double)b0.y; a0 = fma(d, d, a0);
                d = (double)c0.z - (double)b0.z; a0 = fma(d, d, a0);
                d = (double)c0.w - (double)b0.w; a0 = fma(d, d, a0);
                d = (double)c1.x - (double)b1.x; a1 = fma(d, d, a1);
                d = (double)c1.y - (double)b1.y; a1 = fma(d, d, a1);
                d = (double)c1.z - (double)b1.z; a1 = fma(d, d, a1);
                d = (double)c1.w - (double)b1.w; a1 = fma(d, d, a1);
            }
            topk_insert_d<K>(bd, bi, a0 + a1, r);
        }
#pragma unroll
        for (int p = 0; p < K; ++p) {
            double md = bd[0]; int mj = bi[0];
#pragma unroll
            for (int u = 1; u < K; ++u)
                if (lexd(bd[u], bi[u], md, mj)) { md = bd[u]; mj = bi[u]; }
#pragma unroll
            for (int off = 32; off >= 1; off >>= 1) {
                const double od = __shfl_xor(md, off, 64);
                const int    oj = __shfl_xor(mj, off, 64);
                if (lexd(od, oj, md, mj)) { md = od; mj = oj; }
            }
            if (lane == 0) {
                fbd[(size_t)item * K + p] = md;
                fbi[(size_t)item * K + p] = mj;
            }
#pragma unroll
            for (int u = 0; u < K; ++u)
                if (bi[u] == mj) bd[u] = 1e300;
        }
    }
}

// ---------------- merge per-segment partial top-Ks -> final indices ----------------
template<int K>
__global__ __launch_bounds__(256)
void fallback_merge_kernel(const double* __restrict__ fbd, const int* __restrict__ fbi,
                           const int* __restrict__ ovf, const int* __restrict__ novf,
                           int* __restrict__ idx_out, int n) {
    const int tid = threadIdx.x, lane = tid & 63, w = tid >> 6;
    const int nwave = gridDim.x * 4;
    const int total = min(novf[0], MAXF);
    constexpr int E = SEGS * K;
    constexpr int PL = (E + 63) / 64;
    for (int e = blockIdx.x * 4 + w; e < total; e += nwave) {
        const int q = ovf[e];
        double dv[PL]; int jv[PL];
#pragma unroll
        for (int u = 0; u < PL; ++u) {
            const int c = u * 64 + lane;
            if (c < E) { dv[u] = fbd[(size_t)e * E + c]; jv[u] = fbi[(size_t)e * E + c]; }
            else       { dv[u] = 1e300;                  jv[u] = 0x7fffffff; }
        }
#pragma unroll
        for (int p = 0; p < K; ++p) {
            double md = dv[0]; int mj = jv[0];
#pragma unroll
            for (int u = 1; u < PL; ++u)
                if (lexd(dv[u], jv[u], md, mj)) { md = dv[u]; mj = jv[u]; }
#pragma unroll
            for (int off = 32; off >= 1; off >>= 1) {
                const double od = __shfl_xor(md, off, 64);
                const int    oj = __shfl_xor(mj, off, 64);
                if (lexd(od, oj, md, mj)) { md = od; mj = oj; }
            }
            if (lane == 0) idx_out[(size_t)q * K + p] = mj;
#pragma unroll
            for (int u = 0; u < PL; ++u)
                if (jv[u] == mj) dv[u] = 1e300;
        }
    }
}

// ---------------- serial fallback (only for e >= MAXF; never expected) ----------------
template<int D, int K>
__global__ __launch_bounds__(256)
void fallback_kernel(const float* __restrict__ X, const int* __restrict__ ovf,
                     const int* __restrict__ novf, int* __restrict__ idx_out, int n) {
    __shared__ float xq[4][D];
    const int tid = threadIdx.x, lane = tid & 63, w = tid >> 6;
    const int gw = blockIdx.x * 4 + w;
    const int total = novf[0];
    for (int e = MAXF + gw; e < total; e += gridDim.x * 4) {
        const int q = ovf[e];
        if (lane < D / 4)
            *(float4*)(&xq[w][lane * 4]) = *(const float4*)(X + (size_t)q * D + lane * 4);
        double bd[K]; int bi[K];
#pragma unroll
        for (int p = 0; p < K; ++p) { bd[p] = 1e300; bi[p] = 0x7fffffff; }
        for (int r = lane; r < n; r += 64) {
            if (r == q) continue;
            const float4* xr = (const float4*)(X + (size_t)r * D);
            double a0 = 0.0, a1 = 0.0;
#pragma unroll
            for (int t = 0; t < D / 8; ++t) {
                const float4 b0 = xr[2 * t], b1 = xr[2 * t + 1];
                const float4 c0 = *(const float4*)(&xq[w][8 * t]);
                const float4 c1 = *(const float4*)(&xq[w][8 * t + 4]);
                double d;
                d = (double)c0.x - (double)b0.x; a0 = fma(d, d, a0);
                d = (double)c0.y - (double)b0.y; a0 = fma(d, d, a0);
                d = (double)c0.z - (double)b0.z; a0 = fma(d, d, a0);
                d = (double)c0.w - (double)b0.w; a0 = fma(d, d, a0);
                d = (double)c1.x - (double)b1.x; a1 = fma(d, d, a1);
                d = (double)c1.y - (double)b1.y; a1 = fma(d, d, a1);
                d = (double)c1.z - (double)b1.z; a1 = fma(d, d, a1);
                d = (double)c1.w - (double)b1.w; a1 = fma(d, d, a1);
            }
            topk_insert_d<K>(bd, bi, a0 + a1, r);
        }
#pragma unroll
        for (int p = 0; p < K; ++p) {
            double md = bd[0]; int mj = bi[0];
#pragma unroll
            for (int u = 1; u < K; ++u)
                if (lexd(bd[u], bi[u], md, mj)) { md = bd[u]; mj = bi[u]; }
#pragma unroll
            for (int off = 32; off >= 1; off >>= 1) {
                const double od = __shfl_xor(md, off, 64);
                const int    oj = __shfl_xor(mj, off, 64);
                if (lexd(od, oj, md, mj)) { md = od; mj = oj; }
            }
            if (lane == 0) idx_out[(size_t)q * K + p] = mj;
#pragma unroll
            for (int u = 0; u < K; ++u)
                if (bi[u] == mj) bd[u] = 1e300;
        }
    }
}

// ---------------- T = X @ W^T (bias folded into gather-max), PB=32 rows/block ---------
template<int D>
__global__ __launch_bounds__(256)
void lin_kernel(const float* __restrict__ X, const float* __restrict__ W,
                float* __restrict__ T, int n) {
    constexpr int PB = 32;
    __shared__ float Wlds[D * HID];
    __shared__ float Xlds[PB * D];
    const int tid = threadIdx.x;
    const int p0 = blockIdx.x * PB;

    {
        const int h = tid & 127;
        const int hf = tid >> 7;
#pragma unroll
        for (int u = 0; u < D / 8; ++u) {
            const int d0 = hf * (D / 2) + u * 4;
            const float4 v = *(const float4*)(W + (size_t)h * D + d0);
            Wlds[(d0 + 0) * HID + h] = v.x;
            Wlds[(d0 + 1) * HID + h] = v.y;
            Wlds[(d0 + 2) * HID + h] = v.z;
            Wlds[(d0 + 3) * HID + h] = v.w;
        }
    }
    {
        const int rr = tid & 31;
        const int g = tid >> 5;             // 0..7
        constexpr int DG = D / 8;
        const int p = p0 + rr;
        const bool ok = p < n;
#pragma unroll
        for (int u = 0; u < DG / 4; ++u) {
            const int d0 = g * DG + u * 4;
            const float4 v = ok ? *(const float4*)(X + (size_t)p * D + d0)
                                : make_float4(0.f, 0.f, 0.f, 0.f);
            *(float4*)(&Xlds[rr * D + d0]) = v;
        }
    }
    __syncthreads();

    const int pp = tid >> 4;   // 0..15; handles rows pp and pp+16
    const int hh = tid & 15;
    float acc0[8], acc1[8];
#pragma unroll
    for (int e = 0; e < 8; ++e) { acc0[e] = 0.f; acc1[e] = 0.f; }
#pragma unroll 4
    for (int d = 0; d < D; ++d) {
        const float xa0 = Xlds[pp * D + d];
        const float xa1 = Xlds[(pp + 16) * D + d];
#pragma unroll
        for (int e = 0; e < 8; ++e) {
            const float wv = Wlds[d * HID + hh + 16 * e];
            acc0[e] = fmaf(xa0, wv, acc0[e]);
            acc1[e] = fmaf(xa1, wv, acc1[e]);
        }
    }
    const int pA = p0 + pp, pB = p0 + pp + 16;
    if (pA < n) {
#pragma unroll
        for (int e = 0; e < 8; ++e)
            T[(size_t)pA * HID + hh + 16 * e] = acc0[e];
    }
    if (pB < n) {
#pragma unroll
        for (int e = 0; e < 8; ++e)
            T[(size_t)pB * HID + hh + 16 * e] = acc1[e];
    }
}

// ---------------- h[i,:] = max_j T[idx_j,:] - T[i,:] + b ----------------
template<int K>
__global__ void gathermax_kernel(const float* __restrict__ T, const int* __restrict__ idx,
                                 const float* __restrict__ b, float* __restrict__ out, int n) {
    const int i = blockIdx.x;
    const int h = threadIdx.x;
    float m = -__builtin_inff();
#pragma unroll
    for (int t = 0; t < K; ++t) {
        const int j = idx[(size_t)i * K + t];
        m = fmaxf(m, T[(size_t)j * HID + h]);
    }
    out[(size_t)i * HID + h] = m - T[(size_t)i * HID + h] + b[h];
}

// ---------------- out = h2 @ Wl^T + bl ----------------
__global__ void final_kernel(const float* __restrict__ h2, const float* __restrict__ Wl,
                             const float* __restrict__ bl, float* __restrict__ out, int n) {
    const int t = blockIdx.x * 256 + threadIdx.x;
    const int i = t >> 4;
    const int c = t & 15;
    if (i >= n || c >= 10) return;
    const float* hr = h2 + (size_t)i * HID;
    const float* wr = Wl + (size_t)c * HID;
    float s = 0.f;
#pragma unroll 4
    for (int d = 0; d < HID; ++d) s = fmaf(hr[d], wr[d], s);
    out[(size_t)i * 10 + c] = s + bl[c];
}

extern "C" void kernel_launch(void* const* d_in, const int* in_sizes, int n_in,
                              void* d_out, int out_size, void* d_ws, size_t ws_size,
                              hipStream_t stream) {
    const float* x  = (const float*)d_in[0];
    const float* W1 = (const float*)d_in[1];
    const float* b1 = (const float*)d_in[2];
    const float* W2 = (const float*)d_in[3];
    const float* b2 = (const float*)d_in[4];
    const float* Wl = (const float*)d_in[5];
    const float* bl = (const float*)d_in[6];
    float* out = (float*)d_out;
    const int n = in_sizes[0] / 64;   // 10000
    constexpr int K1 = 5, K2 = 10;

    char* ws = (char*)d_ws;
    size_t off = 0;
    auto alloc = [&](size_t bytes) -> void* {
        void* p = ws + off;
        off = (off + bytes + 255) & ~(size_t)255;
        return p;
    };
    // union region with disjoint lifetimes (knn / fallback / lin phases)
    const size_t cpairB = (size_t)NSPLIT * n * BUDS * 8;         // 30.7 MB
    const size_t smpB   = (size_t)n * SSPL * 4 * K2 * 4;         // 6.4 MB
    const size_t fbdB   = (size_t)MAXF * SEGS * K2 * 8;          // 5.24 MB
    const size_t fbiB   = (size_t)MAXF * SEGS * K2 * 4;          // 2.62 MB
    const size_t TB_    = (size_t)n * HID * 4;                   // 5.12 MB
    size_t regB = cpairB + smpB;
    if (fbdB + fbiB > regB) regB = fbdB + fbiB;
    if (TB_ > regB) regB = TB_;
    char*  region = (char*)alloc(regB);
    float* T1    = (float*)region;
    int2*  cpair = (int2*)region;
    float* smp   = (float*)(region + cpairB);
    double* fbd  = (double*)region;
    int*   fbi   = (int*)(region + fbdB);
    float* h1b  = (float*)alloc((size_t)n * HID * 4);
    float* sqh  = (float*)alloc((size_t)n * 4);
    int*   idx1 = (int*)alloc((size_t)n * K1 * 4);
    int*   idx2 = (int*)alloc((size_t)n * K2 * 4);
    u16*   Xh   = (u16*)alloc((size_t)n * 64 * 2);
    u16*   Hh   = (u16*)alloc((size_t)n * HID * 2);
    float* tau  = (float*)alloc((size_t)n * 4);
    int*   cnt8 = (int*)alloc((size_t)NSPLIT * n * 4);
    double* dkth = (double*)alloc((size_t)n * 8);
    int*   gok  = (int*)alloc((size_t)n * 4);
    int*   ovf  = (int*)alloc((size_t)n * 4);
    int*   novf = (int*)alloc(256);
    float* sqmax = (float*)alloc(256);
    float* T2  = T1;
    float* h2b = h1b;

    const int cps  = (n + NSPLIT - 1) / NSPLIT;   // 625
    const int qbs  = (n + 63) / 64;               // 157 (sample pass)
    const int qbs2 = (n + 127) / 128;             // 79  (main pass, QB=128)
    const int sstr = n / SMP;                     // 9
    const int nb   = (n + 255) / 256;

    // ---- layer 1 (D=64, K=5) ----
    zero_misc_kernel<<<1, 64, 0, stream>>>(novf, sqmax);
    conv_f16_kernel<64><<<nb, 256, 0, stream>>>(x, Xh, sqh, sqmax, n);
    sample_knn_kernel<64, K1><<<dim3(qbs, SSPL), 256, 0, stream>>>(Xh, sqh, smp, n, sstr);
    tau_merge_kernel<K1><<<nb, 256, 0, stream>>>(smp, tau, n);
    knn_main_kernel<64><<<dim3(qbs2, NSPLIT), 256, 0, stream>>>(Xh, sqh, tau, sqmax, cnt8, cpair, n, cps);
    select_kernel<64, K1><<<(n + 3) / 4, 256, 0, stream>>>(x, sqh, sqmax, cpair, cnt8, idx1, dkth, gok, n);
    flag_kernel<K1><<<nb, 256, 0, stream>>>(cnt8, dkth, tau, sqh, sqmax, gok, novf, ovf, n);
    fallback_seg_kernel<64, K1><<<1024, 256, 0, stream>>>(x, ovf, novf, fbd, fbi, n);
    fallback_merge_kernel<K1><<<256, 256, 0, stream>>>(fbd, fbi, ovf, novf, idx1, n);
    fallback_kernel<64, K1><<<256, 256, 0, stream>>>(x, ovf, novf, idx1, n);
    lin_kernel<64><<<(n + 31) / 32, 256, 0, stream>>>(x, W1, T1, n);
    gathermax_kernel<K1><<<n, HID, 0, stream>>>(T1, idx1, b1, h1b, n);

    // ---- layer 2 (D=128, K=10) ----
    zero_misc_kernel<<<1, 64, 0, stream>>>(novf, sqmax);
    conv_f16_kernel<HID><<<nb, 256, 0, stream>>>(h1b, Hh, sqh, sqmax, n);
    sample_knn_kernel<HID, K2><<<dim3(qbs, SSPL), 256, 0, stream>>>(Hh, sqh, smp, n, sstr);
    tau_merge_kernel<K2><<<nb, 256, 0, stream>>>(smp, tau, n);
    knn_main_kernel<HID><<<dim3(qbs2, NSPLIT), 256, 0, stream>>>(Hh, sqh, tau, sqmax, cnt8, cpair, n, cps);
    select_kernel<HID, K2><<<(n + 3) / 4, 256, 0, stream>>>(h1b, sqh, sqmax, cpair, cnt8, idx2, dkth, gok, n);
    flag_kernel<K2><<<nb, 256, 0, stream>>>(cnt8, dkth, tau, sqh, sqmax, gok, novf, ovf, n);
    fallback_seg_kernel<HID, K2><<<1024, 256, 0, stream>>>(h1b, ovf, novf, fbd, fbi, n);
    fallback_merge_kernel<K2><<<256, 256, 0, stream>>>(fbd, fbi, ovf, novf, idx2, n);
    fallback_kernel<HID, K2><<<256, 256, 0, stream>>>(h1b, ovf, novf, idx2, n);
    lin_kernel<HID><<<(n + 31) / 32, 256, 0, stream>>>(h1b, W2, T2, n);
    gathermax_kernel<K2><<<n, HID, 0, stream>>>(T2, idx2, b2, h2b, n);

    // ---- head ----
    final_kernel<<<(n * 16 + 255) / 256, 256, 0, stream>>>(h2b, Wl, bl, out, n);
}